// Round 15
// baseline (320.372 us; speedup 1.0000x reference)
//
#include <hip/hip_runtime.h>
#include <hip/hip_fp16.h>
#include <cstdint>
#include <cstddef>

#define N_NODES 50000
#define N_EDGES 800000
#define DIM_IN  128
#define DIM_OUT 64

// R15: delete the front-end. Each bucket-block SCANS the full dst array
// (3.2MB, L2/L3-resident) and captures its own ~4082 edges directly into
// LDS — no pairs buffer, no gcnt, no reserve, no memset. Co-dispatched
// with the GEMM role (scan is L2-bound, GEMM is MFMA/HBM-bound). h-scale
// moves to kE's gather via dinv[] (R11-proven interior). TWO kernels.
#define B2SHIFT 8                                   // 256 nodes per bucket
#define B2NODES 256
#define NB2     ((N_NODES + B2NODES - 1) / B2NODES) // 196 buckets
#define NE4     (N_EDGES / 4)                       // 200000 int4 edge groups
#define CAPB    4864                                // slots/bucket (mean 4082 + 12 sigma)
#define GROWS   256                                 // gemm rows per 512t unit (8 waves x 32)
#define GEMMB   ((N_NODES + GROWS - 1) / GROWS)     // 196 gemm units
#define NEGRP   ((N_NODES + 31) / 32)               // 1563 kE blocks (32 nodes each)

typedef _Float16 f16x8 __attribute__((ext_vector_type(8)));
typedef float    f32x4 __attribute__((ext_vector_type(4)));

// ---------------------------------------------------------------------------
// kSG: dual-role, 512 threads, 392 blocks, NO grid sync (roles independent).
//   blocks 0..NB2-1   : bucket scan-sort. Stream ALL dst (int4), capture own
//     bucket's (src,dst) into LDS cap[], count bins, scan, LDS counting sort,
//     coalesced csr dump + nodeoff2 + dinv.
//   blocks NB2..391   : MFMA gemm, 256 rows (8 waves x 32, R0 per-wave).
// ---------------------------------------------------------------------------
__global__ __launch_bounds__(512) void kSG(const int* __restrict__ ei,
                                           const float* __restrict__ x,
                                           const float* __restrict__ W,
                                           __half* __restrict__ h,
                                           unsigned short* __restrict__ csr,
                                           int2* __restrict__ nodeoff2,
                                           float* __restrict__ dinv) {
    const int t = threadIdx.x;
    if (blockIdx.x < NB2) {
        // ---- bucket scan-sort (~31 KB LDS) ----
        __shared__ unsigned cap[CAPB];       // captured (src<<16 | dst&0xFFFF)
        __shared__ int cnt[B2NODES];
        __shared__ int cur[B2NODES];
        __shared__ int wsum[4];
        __shared__ int ncap;
        __shared__ unsigned short lcsr[CAPB];
        const int b = blockIdx.x;
        if (t == 0) ncap = 0;
        if (t < B2NODES) cnt[t] = 0;
        __syncthreads();

        {   // scan the full dst stream; capture hits (hit rate ~2%/lane)
            const int4* __restrict__ dst4 = (const int4*)(ei + N_EDGES);
            const int* __restrict__ srcs = ei;
            for (int g = t; g < NE4; g += 512) {
                const int4 d = dst4[g];
                if ((d.x >> B2SHIFT) == b) {
                    const int p = atomicAdd(&ncap, 1);
                    if (p < CAPB) cap[p] = ((unsigned)srcs[4 * g + 0] << 16) | (unsigned)(d.x & 0xFFFF);
                }
                if ((d.y >> B2SHIFT) == b) {
                    const int p = atomicAdd(&ncap, 1);
                    if (p < CAPB) cap[p] = ((unsigned)srcs[4 * g + 1] << 16) | (unsigned)(d.y & 0xFFFF);
                }
                if ((d.z >> B2SHIFT) == b) {
                    const int p = atomicAdd(&ncap, 1);
                    if (p < CAPB) cap[p] = ((unsigned)srcs[4 * g + 2] << 16) | (unsigned)(d.z & 0xFFFF);
                }
                if ((d.w >> B2SHIFT) == b) {
                    const int p = atomicAdd(&ncap, 1);
                    if (p < CAPB) cap[p] = ((unsigned)srcs[4 * g + 3] << 16) | (unsigned)(d.w & 0xFFFF);
                }
            }
        }
        __syncthreads();
        const int total = min(ncap, CAPB);

        for (int i = t; i < total; i += 512)             // count bins
            atomicAdd(&cnt[cap[i] & (B2NODES - 1)], 1);
        __syncthreads();

        // 256-bin exclusive scan (proven interior)
        if (t < B2NODES) {
            const int lane = t & 63;
            const int v = cnt[t];
            int xs = v;
#pragma unroll
            for (int off = 1; off < 64; off <<= 1) {
                int y = __shfl_up(xs, off);
                if (lane >= off) xs += y;
            }
            cur[t] = xs;
            if (lane == 63) wsum[t >> 6] = xs;
        }
        __syncthreads();
        if (t == 0) {
            int acc = 0;
#pragma unroll
            for (int w2 = 0; w2 < 4; ++w2) { const int v2 = wsum[w2]; wsum[w2] = acc; acc += v2; }
        }
        __syncthreads();
        if (t < B2NODES) {
            const int v = cnt[t];
            const int excl = cur[t] - v + wsum[t >> 6];
            const int n = (b << B2SHIFT) + t;
            if (n < N_NODES) {
                nodeoff2[n] = make_int2(b * CAPB + excl, v);
                dinv[n] = rsqrtf((float)(v + 1));
            }
            cur[t] = excl;
        }
        __syncthreads();

        for (int i = t; i < total; i += 512) {           // LDS counting sort
            const unsigned p = cap[i];
            const int q = atomicAdd(&cur[p & (B2NODES - 1)], 1);
            lcsr[q] = (unsigned short)(p >> 16);
        }
        __syncthreads();

        {   // coalesced csr dump (2 ushorts per uint store)
            const int cw = (total + 1) >> 1;
            const unsigned* l32 = (const unsigned*)lcsr;
            unsigned* c32 = (unsigned*)(csr + b * CAPB);
            for (int i2 = t; i2 < cw; i2 += 512) c32[i2] = l32[i2];
        }
    } else {
        // ---- gemm unit: h[n,:] = half(x[n,:] @ W), UNSCALED ----
        // MFMA 16x16x32_f16: A[m=lane&15][k=quad*8+j]; B[k][n=lane&15];
        // C/D: row=quad*4+reg, col=lane&15 (validated R6-R10).
        const int u = blockIdx.x - NB2;
        const int w = t >> 6;                // wave 0..7
        const int l = t & 63;
        const int q = l >> 4;
        const int m16 = l & 15;

        f16x8 bf[4][4];
#pragma unroll
        for (int kc = 0; kc < 4; ++kc)
#pragma unroll
            for (int ct = 0; ct < 4; ++ct) {
                const float* wp = W + (size_t)(kc * 32 + q * 8) * DIM_OUT + ct * 16 + m16;
                f16x8 v;
#pragma unroll
                for (int j = 0; j < 8; ++j) v[j] = (_Float16)wp[(size_t)j * DIM_OUT];
                bf[kc][ct] = v;
            }

        const int base = u * GROWS + w * 32;
#pragma unroll
        for (int rt = 0; rt < 2; ++rt) {
            const int m0 = base + rt * 16;
            int mrow = m0 + m16;
            if (mrow >= N_NODES) mrow = N_NODES - 1;   // clamp (stores guarded)

            f16x8 af[4];
#pragma unroll
            for (int kc = 0; kc < 4; ++kc) {
                const float4* xp = (const float4*)(x + (size_t)mrow * DIM_IN + kc * 32 + q * 8);
                const float4 p0 = xp[0], p1 = xp[1];
                f16x8 a;
                a[0] = (_Float16)p0.x; a[1] = (_Float16)p0.y;
                a[2] = (_Float16)p0.z; a[3] = (_Float16)p0.w;
                a[4] = (_Float16)p1.x; a[5] = (_Float16)p1.y;
                a[6] = (_Float16)p1.z; a[7] = (_Float16)p1.w;
                af[kc] = a;
            }

            f32x4 acc[4];
#pragma unroll
            for (int ct = 0; ct < 4; ++ct) acc[ct] = (f32x4){0.f, 0.f, 0.f, 0.f};
#pragma unroll
            for (int kc = 0; kc < 4; ++kc)
#pragma unroll
                for (int ct = 0; ct < 4; ++ct)
                    acc[ct] = __builtin_amdgcn_mfma_f32_16x16x32_f16(af[kc], bf[kc][ct], acc[ct], 0, 0, 0);

#pragma unroll
            for (int reg = 0; reg < 4; ++reg) {
                const int r = m0 + q * 4 + reg;
                if (r < N_NODES) {
#pragma unroll
                    for (int ct = 0; ct < 4; ++ct)
                        h[(size_t)r * DIM_OUT + ct * 16 + m16] = __float2half(acc[ct][reg]);
                }
            }
        }
    }
}

// ---------------------------------------------------------------------------
// E (R11-proven interior): CSR gather + per-src dinv (fp32 FMA, L2-hot
// 200KB array) + bias + log_softmax. Eighth-wave per node; 8-deep unroll.
// ---------------------------------------------------------------------------
__global__ __launch_bounds__(256) void kE_agg(const int2* __restrict__ nodeoff2,
                                              const unsigned short* __restrict__ csr,
                                              const __half* __restrict__ h,
                                              const float* __restrict__ dinv,
                                              const float* __restrict__ bvec,
                                              float* __restrict__ out) {
    const int t = threadIdx.x;
    const int ew = t >> 3, sl = t & 7;       // eighth-wave id / sub-lane
    const int n = blockIdx.x * 32 + ew;
    if (n >= N_NODES) return;                // unit-uniform guard
    const f16x8* __restrict__ h8 = (const f16x8*)h;

    const int2 off = nodeoff2[n];
    const int s0 = off.x, s1 = off.x + off.y;
    const float di = rsqrtf((float)(off.y + 1));   // == dinv[n]

    const f16x8 hv = h8[(size_t)n * 8 + sl]; // self-loop term (unscaled h)
    float a[8];
#pragma unroll
    for (int j = 0; j < 8; ++j) a[j] = (float)hv[j] * di;

    int i = s0;
    for (; i + 8 <= s1; i += 8) {
        int   c[8];
        float d[8];
        f16x8 v[8];
#pragma unroll
        for (int j = 0; j < 8; ++j) c[j] = csr[i + j];
#pragma unroll
        for (int j = 0; j < 8; ++j) d[j] = dinv[c[j]];         // L2-hot broadcast
#pragma unroll
        for (int j = 0; j < 8; ++j) v[j] = h8[(size_t)c[j] * 8 + sl];
#pragma unroll
        for (int j = 0; j < 8; ++j)
#pragma unroll
            for (int k = 0; k < 8; ++k) a[k] += (float)v[j][k] * d[j];
    }
    for (; i + 4 <= s1; i += 4) {
        const int c0 = csr[i + 0], c1 = csr[i + 1];
        const int c2 = csr[i + 2], c3 = csr[i + 3];
        const float d0 = dinv[c0], d1 = dinv[c1], d2 = dinv[c2], d3 = dinv[c3];
        const f16x8 v0 = h8[(size_t)c0 * 8 + sl];
        const f16x8 v1 = h8[(size_t)c1 * 8 + sl];
        const f16x8 v2 = h8[(size_t)c2 * 8 + sl];
        const f16x8 v3 = h8[(size_t)c3 * 8 + sl];
#pragma unroll
        for (int j = 0; j < 8; ++j)
            a[j] += (float)v0[j] * d0 + (float)v1[j] * d1
                  + (float)v2[j] * d2 + (float)v3[j] * d3;
    }
    for (; i < s1; ++i) {
        const int c = csr[i];
        const float d = dinv[c];
        const f16x8 v0 = h8[(size_t)c * 8 + sl];
#pragma unroll
        for (int j = 0; j < 8; ++j) a[j] += (float)v0[j] * d;
    }

    const float4 b0 = *(const float4*)&bvec[8 * sl];
    const float4 b1 = *(const float4*)&bvec[8 * sl + 4];
    float v[8];
    v[0] = a[0] * di + b0.x; v[1] = a[1] * di + b0.y;
    v[2] = a[2] * di + b0.z; v[3] = a[3] * di + b0.w;
    v[4] = a[4] * di + b1.x; v[5] = a[5] * di + b1.y;
    v[6] = a[6] * di + b1.z; v[7] = a[7] * di + b1.w;

    float m = v[0];
#pragma unroll
    for (int j = 1; j < 8; ++j) m = fmaxf(m, v[j]);
#pragma unroll
    for (int o = 4; o > 0; o >>= 1) m = fmaxf(m, __shfl_xor(m, o));
    float s = 0.f;
#pragma unroll
    for (int j = 0; j < 8; ++j) s += __expf(v[j] - m);
#pragma unroll
    for (int o = 4; o > 0; o >>= 1) s += __shfl_xor(s, o);
    const float ls = m + __logf(s);

    float4 o0, o1;
    o0.x = v[0] - ls; o0.y = v[1] - ls; o0.z = v[2] - ls; o0.w = v[3] - ls;
    o1.x = v[4] - ls; o1.y = v[5] - ls; o1.z = v[6] - ls; o1.w = v[7] - ls;
    *(float4*)&out[(size_t)n * DIM_OUT + 8 * sl]     = o0;
    *(float4*)&out[(size_t)n * DIM_OUT + 8 * sl + 4] = o1;
}

// ---------------------------------------------------------------------------
extern "C" void kernel_launch(void* const* d_in, const int* in_sizes, int n_in,
                              void* d_out, int out_size, void* d_ws, size_t ws_size,
                              hipStream_t stream) {
    const float* x  = (const float*)d_in[0];
    const int*   ei = (const int*)d_in[1];   // [2, E]: row0 = src, row1 = dst
    const float* W  = (const float*)d_in[2];
    const float* b  = (const float*)d_in[3];
    float* out = (float*)d_out;

    // workspace (~9 MB of the 256 MB ws):
    char* ws = (char*)d_ws;
    __half*         h        = (__half*)ws;         ws += (size_t)N_NODES * DIM_OUT * sizeof(__half);
    unsigned short* csr      = (unsigned short*)ws; ws += (size_t)NB2 * CAPB * sizeof(unsigned short);
    int2*           nodeoff2 = (int2*)ws;           ws += (size_t)N_NODES * sizeof(int2);
    float*          dinv     = (float*)ws;          ws += (size_t)N_NODES * sizeof(float);

    kSG    <<<NB2 + GEMMB, 512, 0, stream>>>(ei, x, W, h, csr, nodeoff2, dinv);
    kE_agg <<<NEGRP, 256, 0, stream>>>(nodeoff2, csr, h, dinv, b, out);
}

// Round 16
// 115.145 us; speedup vs baseline: 2.7823x; 2.7823x over previous
//
#include <hip/hip_runtime.h>
#include <hip/hip_fp16.h>
#include <cstdint>
#include <cstddef>

#define N_NODES 50000
#define N_EDGES 800000
#define DIM_IN  128
#define DIM_OUT 64

// FINAL (champion restore): R12 @ 114.13us, the best of 16 rounds.
// Structure: dual-role kFG (bucket-scatter FE + MFMA GEMM co-dispatched),
// per-bucket LDS counting sort with coalesced csr dump + fused h-scale,
// eighth-wave CSR gather + log_softmax.
// Session ledger: R0/R7/R12 (3 distinct pipelines) all converge 114-115us;
// FE redesigns (R2/R5/R8/R9/R10/R14), kSort/kE micro-opts (R13), h-scale
// relocation (R11), coop fusion (R6), 2-pass radix (R9), fixed-run (R10),
// broadcast-scan (R15) all null or regressed. Structural plateau of this
// decomposition; kernels are latency/atomic-bound, not at a HW roofline.
#define B2SHIFT 8                                   // 256 nodes per bucket
#define B2NODES 256
#define NB2     ((N_NODES + B2NODES - 1) / B2NODES) // 196 buckets
#define EB      4096                                // edges per front-end tile
#define SORTB   ((N_EDGES + EB - 1) / EB)           // 196 tiles
#define NE4     (N_EDGES / 4)                       // 200000 int4 edge groups
#define CAPB    4864                                // slots/bucket (mean 4082 + 12 sigma)
#define GROWS   128                                 // gemm rows per 256t unit
#define GEMMB   ((N_NODES + GROWS - 1) / GROWS)     // 391 gemm units
#define GPAD    16                                  // gcnt stride: 1 counter per 64B line
#define NEGRP   ((N_NODES + 31) / 32)               // 1563 kE blocks (32 nodes each)

typedef _Float16 f16x8 __attribute__((ext_vector_type(8)));
typedef float    f32x4 __attribute__((ext_vector_type(4)));

// ---------------------------------------------------------------------------
// FG: dual-role dispatch, 256 threads/block, NO grid sync.
//   blocks 0..SORTB-1 : FE tile, register-resident edges, batched scatter.
//   blocks SORTB..586 : MFMA gemm writing UNSCALED h = half(x @ W).
// ---------------------------------------------------------------------------
__global__ __launch_bounds__(256) void kFG(const int* __restrict__ ei,
                                           int* __restrict__ gcnt,
                                           unsigned* __restrict__ pairs,
                                           const float* __restrict__ x,
                                           const float* __restrict__ W,
                                           __half* __restrict__ h) {
    const int t = threadIdx.x;
    if (blockIdx.x < SORTB) {
        // ---- front-end tile: one edge read, batched scatter ----
        __shared__ int hcnt[B2NODES];
        __shared__ int cur[B2NODES];
        const int blk = blockIdx.x;
        hcnt[t] = 0;                         // blockDim == B2NODES
        __syncthreads();
        const int4* src4 = (const int4*)ei;
        const int4* dst4 = (const int4*)(ei + N_EDGES);
        const int g0 = blk * (EB / 4);

        int4 dv[4], sv[4];
        bool live[4];
#pragma unroll
        for (int it = 0; it < 4; ++it) {     // load ALL edges to registers
            const int g = g0 + it * 256 + t;
            live[it] = (g < NE4);
            if (live[it]) { dv[it] = dst4[g]; sv[it] = src4[g]; }
        }
#pragma unroll
        for (int it = 0; it < 4; ++it) {     // histogram from registers
            if (live[it]) {
                atomicAdd(&hcnt[dv[it].x >> B2SHIFT], 1);
                atomicAdd(&hcnt[dv[it].y >> B2SHIFT], 1);
                atomicAdd(&hcnt[dv[it].z >> B2SHIFT], 1);
                atomicAdd(&hcnt[dv[it].w >> B2SHIFT], 1);
            }
        }
        __syncthreads();
        {                                    // reserve: 1 bucket per thread
            const int c = hcnt[t];
            // t >= NB2 has c == 0 -> no OOB atomic (gcnt sized NB2*GPAD)
            const int base = c ? atomicAdd(&gcnt[t * GPAD], c) : 0;
            cur[t] = t * CAPB + base;
        }
        __syncthreads();
        {   // batched scatter: 16 independent LDS atomics, then 16 stores
            int pos[16];
            int bb[16];
#pragma unroll
            for (int it = 0; it < 4; ++it) {
                if (live[it]) {
                    bb[it * 4 + 0] = dv[it].x >> B2SHIFT;
                    bb[it * 4 + 1] = dv[it].y >> B2SHIFT;
                    bb[it * 4 + 2] = dv[it].z >> B2SHIFT;
                    bb[it * 4 + 3] = dv[it].w >> B2SHIFT;
#pragma unroll
                    for (int c2 = 0; c2 < 4; ++c2)
                        pos[it * 4 + c2] = atomicAdd(&cur[bb[it * 4 + c2]], 1);
                }
            }
#pragma unroll
            for (int it = 0; it < 4; ++it) {
                if (live[it]) {
                    const int p0 = pos[it * 4 + 0], p1 = pos[it * 4 + 1];
                    const int p2 = pos[it * 4 + 2], p3 = pos[it * 4 + 3];
                    if (p0 < bb[it * 4 + 0] * CAPB + CAPB)
                        pairs[p0] = ((unsigned)sv[it].x << 16) | (unsigned)dv[it].x;
                    if (p1 < bb[it * 4 + 1] * CAPB + CAPB)
                        pairs[p1] = ((unsigned)sv[it].y << 16) | (unsigned)dv[it].y;
                    if (p2 < bb[it * 4 + 2] * CAPB + CAPB)
                        pairs[p2] = ((unsigned)sv[it].z << 16) | (unsigned)dv[it].z;
                    if (p3 < bb[it * 4 + 3] * CAPB + CAPB)
                        pairs[p3] = ((unsigned)sv[it].w << 16) | (unsigned)dv[it].w;
                }
            }
        }
    } else {
        // ---- gemm unit: h[n,:] = half(x[n,:] @ W), UNSCALED ----
        // MFMA 16x16x32_f16: A[m=lane&15][k=quad*8+j]; B[k][n=lane&15];
        // C/D: row=quad*4+reg, col=lane&15 (validated R6-R10).
        const int u = blockIdx.x - SORTB;
        const int w = t >> 6;
        const int l = t & 63;
        const int q = l >> 4;
        const int m16 = l & 15;

        f16x8 bf[4][4];
#pragma unroll
        for (int kc = 0; kc < 4; ++kc)
#pragma unroll
            for (int ct = 0; ct < 4; ++ct) {
                const float* wp = W + (size_t)(kc * 32 + q * 8) * DIM_OUT + ct * 16 + m16;
                f16x8 v;
#pragma unroll
                for (int j = 0; j < 8; ++j) v[j] = (_Float16)wp[(size_t)j * DIM_OUT];
                bf[kc][ct] = v;
            }

        const int base = u * GROWS + w * 32;
#pragma unroll
        for (int rt = 0; rt < 2; ++rt) {
            const int m0 = base + rt * 16;
            int mrow = m0 + m16;
            if (mrow >= N_NODES) mrow = N_NODES - 1;   // clamp (stores guarded)

            f16x8 af[4];
#pragma unroll
            for (int kc = 0; kc < 4; ++kc) {
                const float4* xp = (const float4*)(x + (size_t)mrow * DIM_IN + kc * 32 + q * 8);
                const float4 p0 = xp[0], p1 = xp[1];
                f16x8 a;
                a[0] = (_Float16)p0.x; a[1] = (_Float16)p0.y;
                a[2] = (_Float16)p0.z; a[3] = (_Float16)p0.w;
                a[4] = (_Float16)p1.x; a[5] = (_Float16)p1.y;
                a[6] = (_Float16)p1.z; a[7] = (_Float16)p1.w;
                af[kc] = a;
            }

            f32x4 acc[4];
#pragma unroll
            for (int ct = 0; ct < 4; ++ct) acc[ct] = (f32x4){0.f, 0.f, 0.f, 0.f};
#pragma unroll
            for (int kc = 0; kc < 4; ++kc)
#pragma unroll
                for (int ct = 0; ct < 4; ++ct)
                    acc[ct] = __builtin_amdgcn_mfma_f32_16x16x32_f16(af[kc], bf[kc][ct], acc[ct], 0, 0, 0);

#pragma unroll
            for (int reg = 0; reg < 4; ++reg) {
                const int r = m0 + q * 4 + reg;
                if (r < N_NODES) {
#pragma unroll
                    for (int ct = 0; ct < 4; ++ct)
                        h[(size_t)r * DIM_OUT + ct * 16 + m16] = __float2half(acc[ct][reg]);
                }
            }
        }
    }
}

// ---------------------------------------------------------------------------
// Sort: one block per 256-node bucket (512 threads):
//   count -> scan -> LDS scatter -> coalesced csr dump + nodeoff2 +
//   in-place h *= rsqrt(deg+1).
// ---------------------------------------------------------------------------
__global__ __launch_bounds__(512) void kSort(const unsigned* __restrict__ pairs,
                                             const int* __restrict__ gcnt,
                                             unsigned short* __restrict__ csr,
                                             int2* __restrict__ nodeoff2,
                                             __half* __restrict__ h) {
    __shared__ int cnt[B2NODES];
    __shared__ int cur[B2NODES];
    __shared__ float sdinv[B2NODES];
    __shared__ int wsum[4];
    __shared__ unsigned short lcsr[CAPB];    // 9.7 KB
    const int b = blockIdx.x, t = threadIdx.x;
    const int eb = b * CAPB;
    const int count = min(gcnt[b * GPAD], CAPB);
    const int ee = eb + count;

    if (t < B2NODES) cnt[t] = 0;
    __syncthreads();

    {   // count
        int i = eb + t;
        for (; i + 1536 < ee; i += 2048) {
            const unsigned p0 = pairs[i];
            const unsigned p1 = pairs[i + 512];
            const unsigned p2 = pairs[i + 1024];
            const unsigned p3 = pairs[i + 1536];
            atomicAdd(&cnt[p0 & (B2NODES - 1)], 1);
            atomicAdd(&cnt[p1 & (B2NODES - 1)], 1);
            atomicAdd(&cnt[p2 & (B2NODES - 1)], 1);
            atomicAdd(&cnt[p3 & (B2NODES - 1)], 1);
        }
        for (; i < ee; i += 512) atomicAdd(&cnt[pairs[i] & (B2NODES - 1)], 1);
    }
    __syncthreads();

    // 256-bin exclusive scan: intra-wave shuffle scan + cross-wave combine
    if (t < B2NODES) {
        const int lane = t & 63;
        const int v = cnt[t];
        int xs = v;
#pragma unroll
        for (int off = 1; off < 64; off <<= 1) {
            int y = __shfl_up(xs, off);
            if (lane >= off) xs += y;
        }
        cur[t] = xs;                         // intra-wave inclusive
        if (lane == 63) wsum[t >> 6] = xs;
    }
    __syncthreads();
    if (t == 0) {
        int acc = 0;
#pragma unroll
        for (int w2 = 0; w2 < 4; ++w2) { const int v2 = wsum[w2]; wsum[w2] = acc; acc += v2; }
    }
    __syncthreads();
    if (t < B2NODES) {
        const int v = cnt[t];
        const int excl = cur[t] - v + wsum[t >> 6];
        sdinv[t] = rsqrtf((float)(v + 1));
        const int n = (b << B2SHIFT) + t;
        if (n < N_NODES) nodeoff2[n] = make_int2(eb + excl, v);
        cur[t] = excl;                       // bucket-local scatter offsets
    }
    __syncthreads();

    for (int i = eb + t; i < ee; i += 512) { // LDS scatter
        const unsigned p = pairs[i];
        const int q = atomicAdd(&cur[p & (B2NODES - 1)], 1);
        lcsr[q] = (unsigned short)(p >> 16);
    }
    __syncthreads();

    {   // coalesced csr dump (2 ushorts per uint store)
        const int cw = (count + 1) >> 1;
        const unsigned* l32 = (const unsigned*)lcsr;
        unsigned* c32 = (unsigned*)(csr + eb);
        for (int i2 = t; i2 < cw; i2 += 512) c32[i2] = l32[i2];
    }
    {   // in-place h-scale for this bucket's 256 nodes (contiguous 32 KB)
        f16x8* h8w = (f16x8*)h;
        for (int idx = t; idx < B2NODES * 8; idx += 512) {
            const int r = idx >> 3;
            const int n = (b << B2SHIFT) + r;
            if (n < N_NODES) {
                const float d = sdinv[r];
                f16x8 v = h8w[(size_t)n * 8 + (idx & 7)];
#pragma unroll
                for (int j = 0; j < 8; ++j) v[j] = (_Float16)((float)v[j] * d);
                h8w[(size_t)n * 8 + (idx & 7)] = v;
            }
        }
    }
}

// ---------------------------------------------------------------------------
// E: CSR gather + bias + log_softmax (pre-scaled h). Eighth-wave per node;
// 8-deep unroll (16B f16x8 loads, 32 nodes/block, 1563 blocks).
// ---------------------------------------------------------------------------
__global__ __launch_bounds__(256) void kE_agg(const int2* __restrict__ nodeoff2,
                                              const unsigned short* __restrict__ csr,
                                              const __half* __restrict__ h,
                                              const float* __restrict__ bvec,
                                              float* __restrict__ out) {
    const int t = threadIdx.x;
    const int ew = t >> 3, sl = t & 7;       // eighth-wave id / sub-lane
    const int n = blockIdx.x * 32 + ew;
    if (n >= N_NODES) return;                // unit-uniform guard
    const f16x8* __restrict__ h8 = (const f16x8*)h;

    const int2 off = nodeoff2[n];
    const int s0 = off.x, s1 = off.x + off.y;

    const f16x8 hv = h8[(size_t)n * 8 + sl]; // self-loop term (scaled)
    float a[8];
#pragma unroll
    for (int j = 0; j < 8; ++j) a[j] = (float)hv[j];

    int i = s0;
    for (; i + 8 <= s1; i += 8) {
        int c[8];
        f16x8 v[8];
#pragma unroll
        for (int j = 0; j < 8; ++j) c[j] = csr[i + j];
#pragma unroll
        for (int j = 0; j < 8; ++j) v[j] = h8[(size_t)c[j] * 8 + sl];
#pragma unroll
        for (int j = 0; j < 8; ++j)
#pragma unroll
            for (int k = 0; k < 8; ++k) a[k] += (float)v[j][k];
    }
    for (; i + 4 <= s1; i += 4) {
        const int c0 = csr[i + 0];
        const int c1 = csr[i + 1];
        const int c2 = csr[i + 2];
        const int c3 = csr[i + 3];
        const f16x8 v0 = h8[(size_t)c0 * 8 + sl];
        const f16x8 v1 = h8[(size_t)c1 * 8 + sl];
        const f16x8 v2 = h8[(size_t)c2 * 8 + sl];
        const f16x8 v3 = h8[(size_t)c3 * 8 + sl];
#pragma unroll
        for (int j = 0; j < 8; ++j)
            a[j] += (float)v0[j] + (float)v1[j] + (float)v2[j] + (float)v3[j];
    }
    for (; i < s1; ++i) {
        const f16x8 v0 = h8[(size_t)csr[i] * 8 + sl];
#pragma unroll
        for (int j = 0; j < 8; ++j) a[j] += (float)v0[j];
    }

    const float4 b0 = *(const float4*)&bvec[8 * sl];
    const float4 b1 = *(const float4*)&bvec[8 * sl + 4];
    const float di = rsqrtf((float)(off.y + 1));
    float v[8];
    v[0] = a[0] * di + b0.x; v[1] = a[1] * di + b0.y;
    v[2] = a[2] * di + b0.z; v[3] = a[3] * di + b0.w;
    v[4] = a[4] * di + b1.x; v[5] = a[5] * di + b1.y;
    v[6] = a[6] * di + b1.z; v[7] = a[7] * di + b1.w;

    float m = v[0];
#pragma unroll
    for (int j = 1; j < 8; ++j) m = fmaxf(m, v[j]);
#pragma unroll
    for (int o = 4; o > 0; o >>= 1) m = fmaxf(m, __shfl_xor(m, o));
    float s = 0.f;
#pragma unroll
    for (int j = 0; j < 8; ++j) s += __expf(v[j] - m);
#pragma unroll
    for (int o = 4; o > 0; o >>= 1) s += __shfl_xor(s, o);
    const float ls = m + __logf(s);

    float4 o0, o1;
    o0.x = v[0] - ls; o0.y = v[1] - ls; o0.z = v[2] - ls; o0.w = v[3] - ls;
    o1.x = v[4] - ls; o1.y = v[5] - ls; o1.z = v[6] - ls; o1.w = v[7] - ls;
    *(float4*)&out[(size_t)n * DIM_OUT + 8 * sl]     = o0;
    *(float4*)&out[(size_t)n * DIM_OUT + 8 * sl + 4] = o1;
}

// ---------------------------------------------------------------------------
extern "C" void kernel_launch(void* const* d_in, const int* in_sizes, int n_in,
                              void* d_out, int out_size, void* d_ws, size_t ws_size,
                              hipStream_t stream) {
    const float* x  = (const float*)d_in[0];
    const int*   ei = (const int*)d_in[1];   // [2, E]: row0 = src, row1 = dst
    const float* W  = (const float*)d_in[2];
    const float* b  = (const float*)d_in[3];
    float* out = (float*)d_out;

    // workspace (~13 MB of the 256 MB ws):
    char* ws = (char*)d_ws;
    __half*         h        = (__half*)ws;         ws += (size_t)N_NODES * DIM_OUT * sizeof(__half);
    unsigned*       pairs    = (unsigned*)ws;       ws += (size_t)NB2 * CAPB * sizeof(unsigned);
    unsigned short* csr      = (unsigned short*)ws; ws += (size_t)NB2 * CAPB * sizeof(unsigned short);
    int2*           nodeoff2 = (int2*)ws;           ws += (size_t)N_NODES * sizeof(int2);
    int*            gcnt     = (int*)ws;            ws += (size_t)NB2 * GPAD * sizeof(int);

    hipMemsetAsync(gcnt, 0, (size_t)NB2 * GPAD * sizeof(int), stream);
    kFG    <<<SORTB + GEMMB, 256, 0, stream>>>(ei, gcnt, pairs, x, W, h);
    kSort  <<<NB2, 512, 0, stream>>>(pairs, gcnt, csr, nodeoff2, h);
    kE_agg <<<NEGRP, 256, 0, stream>>>(nodeoff2, csr, h, b, out);
}